// Round 1
// baseline (314.953 us; speedup 1.0000x reference)
//
#include <hip/hip_runtime.h>
#include <hip/hip_bf16.h>

#define BATCH 8192
#define DIM   1024
#define INV_TAU (1.0f / 0.07f)
#define TOPM 0.95f
#define BOTM 0.05f

#define BM 128
#define BN 128
#define BK 64

typedef __attribute__((ext_vector_type(4))) float f32x4;
typedef __attribute__((ext_vector_type(8))) short bf16x8;

typedef __attribute__((address_space(3))) void       lds_void_t;
typedef const __attribute__((address_space(1))) void gbl_void_t;

__device__ inline void async_copy16(const void* g, void* l) {
    __builtin_amdgcn_global_load_lds((gbl_void_t*)g, (lds_void_t*)l, 16, 0, 0);
}

__device__ inline unsigned short f2bf(float f) {
    __hip_bfloat16 h = __float2bfloat16(f);
    return *reinterpret_cast<unsigned short*>(&h);
}

// ---------------------------------------------------------------------------
// Kernel 1: per-row L2 norms, exact fp32 pos (diag similarity), bf16 writes,
// and zero-init of the per-row accumulators (S, cnt).
// One block per row pair; 256 threads, one float4 each (DIM=1024).
// ---------------------------------------------------------------------------
__global__ __launch_bounds__(256) void prep_kernel(
    const float* __restrict__ A, const float* __restrict__ B,
    unsigned short* __restrict__ An, unsigned short* __restrict__ Bn,
    float* __restrict__ pos, float* __restrict__ S, unsigned int* __restrict__ cnt)
{
    int row = blockIdx.x;
    int t = threadIdx.x;
    const float4* a4 = (const float4*)(A + (size_t)row * DIM);
    const float4* b4 = (const float4*)(B + (size_t)row * DIM);
    float4 av = a4[t];
    float4 bv = b4[t];
    float sa = av.x*av.x + av.y*av.y + av.z*av.z + av.w*av.w;
    float sb = bv.x*bv.x + bv.y*bv.y + bv.z*bv.z + bv.w*bv.w;
    float dp = av.x*bv.x + av.y*bv.y + av.z*bv.z + av.w*bv.w;
    #pragma unroll
    for (int d = 32; d > 0; d >>= 1) {
        sa += __shfl_down(sa, d);
        sb += __shfl_down(sb, d);
        dp += __shfl_down(dp, d);
    }
    __shared__ float red[3][4];
    int lane = t & 63, w = t >> 6;
    if (lane == 0) { red[0][w] = sa; red[1][w] = sb; red[2][w] = dp; }
    __syncthreads();
    sa = red[0][0] + red[0][1] + red[0][2] + red[0][3];
    sb = red[1][0] + red[1][1] + red[1][2] + red[1][3];
    dp = red[2][0] + red[2][1] + red[2][2] + red[2][3];
    float ra = rsqrtf(sa);
    float rb = rsqrtf(sb);
    if (t == 0) {
        pos[row] = dp * ra * rb;
        S[row] = 0.0f;
        cnt[row] = 0u;
    }
    ushort4 oa, ob;
    oa.x = f2bf(av.x * ra); oa.y = f2bf(av.y * ra);
    oa.z = f2bf(av.z * ra); oa.w = f2bf(av.w * ra);
    ob.x = f2bf(bv.x * rb); ob.y = f2bf(bv.y * rb);
    ob.z = f2bf(bv.z * rb); ob.w = f2bf(bv.w * rb);
    ((ushort4*)(An + (size_t)row * DIM))[t] = oa;
    ((ushort4*)(Bn + (size_t)row * DIM))[t] = ob;
}

// ---------------------------------------------------------------------------
// Kernel 2: fused sim GEMM + masked exp-sum epilogue.
// 128x128 tile, BK=64, 4 waves (2x2 of 64x64), 16x16x32 bf16 MFMA.
// LDS: linear dest for global_load_lds; XOR-swizzled source + swizzled
// ds_read (both-sides rule) to avoid the 128B-row 16-way bank conflict.
// ---------------------------------------------------------------------------
__global__ __launch_bounds__(256) void sim_loss_kernel(
    const unsigned short* __restrict__ An, const unsigned short* __restrict__ Bn,
    const float* __restrict__ pos, float* __restrict__ S, unsigned int* __restrict__ cnt)
{
    __shared__ unsigned short sA[BM * BK];   // 16 KB, row-major [128][64], swizzled content
    __shared__ unsigned short sB[BN * BK];   // 16 KB

    int tid  = threadIdx.x;
    int lane = tid & 63;
    int wave = tid >> 6;
    int wm = wave >> 1, wn = wave & 1;   // 2x2 wave grid, 64x64 each
    int fr = lane & 15;                  // fragment row/col within 16
    int q  = lane >> 4;                  // lane quarter -> k-slice / acc row group

    int by = blockIdx.y, bx = blockIdx.x;
    int rowBase = by * BM, colBase = bx * BN;

    f32x4 acc[4][4] = {};

    // staging geometry: each thread stages 16B per issue; 4 issues cover 128x64 bf16.
    // linear LDS offset o = s*4096 + tid*16 -> row = s*32 + tid/8, col byte = (tid&7)*16
    int srow = tid >> 3;            // row within a 32-row chunk
    int cb   = (tid & 7) * 16;      // dest byte col within 128B row

    for (int k0 = 0; k0 < DIM; k0 += BK) {
        #pragma unroll
        for (int s = 0; s < 4; ++s) {
            int row = s * 32 + srow;
            int scb = cb ^ ((row & 7) << 4);   // pre-swizzled SOURCE col byte
            const unsigned short* ga = An + (size_t)(rowBase + row) * DIM + k0 + (scb >> 1);
            const unsigned short* gb = Bn + (size_t)(colBase + row) * DIM + k0 + (scb >> 1);
            async_copy16(ga, (char*)sA + s * 4096 + tid * 16);
            async_copy16(gb, (char*)sB + s * 4096 + tid * 16);
        }
        __syncthreads();   // compiler emits vmcnt(0) drain before barrier

        #pragma unroll
        for (int kk = 0; kk < BK; kk += 32) {
            bf16x8 a[4], b[4];
            int cbyte = (kk + q * 8) * 2;
            #pragma unroll
            for (int m = 0; m < 4; ++m) {
                int r = wm * 64 + m * 16 + fr;
                int addr = r * 128 + (cbyte ^ ((r & 7) << 4));   // swizzled READ
                a[m] = *(const bf16x8*)((const char*)sA + addr);
            }
            #pragma unroll
            for (int n = 0; n < 4; ++n) {
                int r = wn * 64 + n * 16 + fr;
                int addr = r * 128 + (cbyte ^ ((r & 7) << 4));
                b[n] = *(const bf16x8*)((const char*)sB + addr);
            }
            #pragma unroll
            for (int m = 0; m < 4; ++m)
                #pragma unroll
                for (int n = 0; n < 4; ++n)
                    acc[m][n] = __builtin_amdgcn_mfma_f32_16x16x32_bf16(
                        a[m], b[n], acc[m][n], 0, 0, 0);
        }
        __syncthreads();   // reads done before next stage overwrites
    }

    // Epilogue: C/D mapping col = lane&15 (fr), row = q*4 + reg j.
    // masked term: sim in [0.05p, 0.95p], not diagonal -> exp((sim-p)/tau), each < 1.
    #pragma unroll
    for (int m = 0; m < 4; ++m) {
        #pragma unroll
        for (int j = 0; j < 4; ++j) {
            int i = rowBase + wm * 64 + m * 16 + q * 4 + j;
            float p  = pos[i];
            float up = TOPM * p, lo = BOTM * p;
            float rs = 0.0f;
            int   rc = 0;
            #pragma unroll
            for (int n = 0; n < 4; ++n) {
                float sv = acc[m][n][j];
                int col = colBase + wn * 64 + n * 16 + fr;
                if (sv <= up && sv >= lo && col != i) {
                    rs += __expf((sv - p) * INV_TAU);
                    rc += 1;
                }
            }
            // reduce across the 16 lanes of this quarter (same row i, cols vary)
            #pragma unroll
            for (int d = 1; d < 16; d <<= 1) {
                rs += __shfl_xor(rs, d);
                rc += __shfl_xor(rc, d);
            }
            if (fr == 0) {
                atomicAdd(&S[i], rs);
                atomicAdd(&cnt[i], (unsigned int)rc);
            }
        }
    }
}

// ---------------------------------------------------------------------------
// Kernel 3: per_row = log1p(S_i) for rows with >=1 negative; mean over valid.
// ---------------------------------------------------------------------------
__global__ __launch_bounds__(256) void finalize_kernel(
    const float* __restrict__ S, const unsigned int* __restrict__ cnt,
    float* __restrict__ out)
{
    int t = threadIdx.x;
    float tot = 0.0f;
    int c = 0;
    for (int i = t; i < BATCH; i += 256) {
        if (cnt[i] > 0u) { tot += log1pf(S[i]); c += 1; }
    }
    #pragma unroll
    for (int d = 32; d > 0; d >>= 1) {
        tot += __shfl_down(tot, d);
        c   += __shfl_down(c, d);
    }
    __shared__ float st[4];
    __shared__ int   sc[4];
    int lane = t & 63, w = t >> 6;
    if (lane == 0) { st[w] = tot; sc[w] = c; }
    __syncthreads();
    if (t == 0) {
        float T = st[0] + st[1] + st[2] + st[3];
        int   C = sc[0] + sc[1] + sc[2] + sc[3];
        out[0] = T / (float)(C > 0 ? C : 1);
    }
}

extern "C" void kernel_launch(void* const* d_in, const int* in_sizes, int n_in,
                              void* d_out, int out_size, void* d_ws, size_t ws_size,
                              hipStream_t stream) {
    const float* A = (const float*)d_in[0];
    const float* B = (const float*)d_in[1];

    char* ws = (char*)d_ws;
    unsigned short* An = (unsigned short*)ws;
    unsigned short* Bn = An + (size_t)BATCH * DIM;
    float* pos = (float*)(Bn + (size_t)BATCH * DIM);
    float* S   = pos + BATCH;
    unsigned int* cnt = (unsigned int*)(S + BATCH);
    float* out = (float*)d_out;

    prep_kernel<<<BATCH, 256, 0, stream>>>(A, B, An, Bn, pos, S, cnt);
    dim3 grid(BATCH / BN, BATCH / BM);
    sim_loss_kernel<<<grid, 256, 0, stream>>>(An, Bn, pos, S, cnt);
    finalize_kernel<<<1, 256, 0, stream>>>(S, cnt, out);
}

// Round 2
// 249.174 us; speedup vs baseline: 1.2640x; 1.2640x over previous
//
#include <hip/hip_runtime.h>
#include <hip/hip_bf16.h>

#define BATCH 8192
#define DIM   1024
#define INV_TAU (1.0f / 0.07f)
#define TOPM 0.95f
#define BOTM 0.05f

#define BM 256
#define BN 256
#define BK 64
#define NT (DIM / BK)   // 16 K-tiles

typedef __attribute__((ext_vector_type(4))) float f32x4;
typedef __attribute__((ext_vector_type(8))) short bf16x8;

typedef __attribute__((address_space(3))) void       lds_void_t;
typedef const __attribute__((address_space(1))) void gbl_void_t;

__device__ inline void async_copy16(const void* g, void* l) {
    __builtin_amdgcn_global_load_lds((gbl_void_t*)g, (lds_void_t*)l, 16, 0, 0);
}

__device__ inline unsigned short f2bf(float f) {
    __hip_bfloat16 h = __float2bfloat16(f);
    return *reinterpret_cast<unsigned short*>(&h);
}

// ---------------------------------------------------------------------------
// Kernel 1: per-row L2 norms, exact fp32 pos (diag similarity), bf16 writes,
// zero-init of per-row accumulator S.
// ---------------------------------------------------------------------------
__global__ __launch_bounds__(256) void prep_kernel(
    const float* __restrict__ A, const float* __restrict__ B,
    unsigned short* __restrict__ An, unsigned short* __restrict__ Bn,
    float* __restrict__ pos, float* __restrict__ S)
{
    int row = blockIdx.x;
    int t = threadIdx.x;
    const float4* a4 = (const float4*)(A + (size_t)row * DIM);
    const float4* b4 = (const float4*)(B + (size_t)row * DIM);
    float4 av = a4[t];
    float4 bv = b4[t];
    float sa = av.x*av.x + av.y*av.y + av.z*av.z + av.w*av.w;
    float sb = bv.x*bv.x + bv.y*bv.y + bv.z*bv.z + bv.w*bv.w;
    float dp = av.x*bv.x + av.y*bv.y + av.z*bv.z + av.w*bv.w;
    #pragma unroll
    for (int d = 32; d > 0; d >>= 1) {
        sa += __shfl_down(sa, d);
        sb += __shfl_down(sb, d);
        dp += __shfl_down(dp, d);
    }
    __shared__ float red[3][4];
    int lane = t & 63, w = t >> 6;
    if (lane == 0) { red[0][w] = sa; red[1][w] = sb; red[2][w] = dp; }
    __syncthreads();
    sa = red[0][0] + red[0][1] + red[0][2] + red[0][3];
    sb = red[1][0] + red[1][1] + red[1][2] + red[1][3];
    dp = red[2][0] + red[2][1] + red[2][2] + red[2][3];
    float ra = rsqrtf(sa);
    float rb = rsqrtf(sb);
    if (t == 0) {
        pos[row] = dp * ra * rb;
        S[row] = 0.0f;
    }
    ushort4 oa, ob;
    oa.x = f2bf(av.x * ra); oa.y = f2bf(av.y * ra);
    oa.z = f2bf(av.z * ra); oa.w = f2bf(av.w * ra);
    ob.x = f2bf(bv.x * rb); ob.y = f2bf(bv.y * rb);
    ob.z = f2bf(bv.z * rb); ob.w = f2bf(bv.w * rb);
    ((ushort4*)(An + (size_t)row * DIM))[t] = oa;
    ((ushort4*)(Bn + (size_t)row * DIM))[t] = ob;
}

// ---------------------------------------------------------------------------
// Kernel 2: 256x256-tile 8-phase pipelined MFMA GEMM + fused masked exp-sum.
// 8 waves (2M x 4N), per-wave 128x64 output, BK=64, double-buffered 128 KiB
// LDS, counted vmcnt(4) once per K-tile (T3+T4), setprio around MFMA (T5),
// both-sides XOR swizzle (T2), XCD-aware block swizzle (T1).
//
// Staging schedule (tile t computed from buf p = t&1):
//   P1: ds a(mh0) 8 + b(nh0) 4 | stage A(t+1) h0 -> A[p^1] | MFMA (mh0,nh0)
//   P2: ds b(nh1) 4            | stage A(t+1) h1 -> A[p^1] | MFMA (mh0,nh1)
//   P3: ds a(mh1) 8            | stage B(t+2) h0 -> B[p]   | MFMA (mh1,nh1)
//   P4: (no ds)                | stage B(t+2) h1 -> B[p]   | MFMA (mh1,nh0)
//       then vmcnt(4): drains A(t+1)+B(t+1); leaves B(t+2)'s 4 in flight.
// A[p^1] is free after P3(t-1); B[p] is free after P2(t). Never vmcnt(0).
// ---------------------------------------------------------------------------
__global__ __launch_bounds__(512, 2) void sim_loss_kernel(
    const unsigned short* __restrict__ An, const unsigned short* __restrict__ Bn,
    const float* __restrict__ pos, float* __restrict__ S)
{
    __shared__ char lds[131072];   // A[2]: 0,32768 ; B[2]: 65536, 98304

    int tid  = threadIdx.x;
    int lane = tid & 63;
    int wave = tid >> 6;
    int wm = wave >> 2, wn = wave & 3;   // 2x4 wave grid, 128x64 per wave
    int fr = lane & 15;
    int q  = lane >> 4;

    // T1: XCD-aware bijective block swizzle (1024 blocks, 8 XCDs, chunk 128)
    int bid = blockIdx.x;
    int swz = (bid & 7) * 128 + (bid >> 3);
    int by = swz >> 5, bx = swz & 31;
    int rowBase = by * BM, colBase = bx * BN;

    f32x4 acc[8][4] = {};
    bf16x8 a[4][2];      // current mh half: 4 m-frags x 2 k-slices
    bf16x8 b[2][2][2];   // both nh halves: [nh][n][kk]

    // ds_read addressing (read-side swizzle: row&7 == fr&7 for all frags)
    int sw = (fr & 7) << 4;
    int c0 = (q * 16) ^ sw;
    int c1 = (64 + q * 16) ^ sw;
    int aRow = (wm * 128 + fr) * 128;
    int bRow = (wn * 64 + fr) * 128;

    // staging addressing (source-side swizzle, linear LDS dest)
    int strow = tid >> 3;                                  // 0..63
    int scb   = ((tid & 7) * 16) ^ ((strow & 7) << 4);
    const char* gA = (const char*)An + (size_t)(rowBase + strow) * 2048 + scb;
    const char* gB = (const char*)Bn + (size_t)(colBase + strow) * 2048 + scb;
    int ldst = tid * 16;

#define STAGE(gbase, u, h, ldsdst) do {                                              \
    async_copy16((gbase) + (size_t)(h) * 262144 + (size_t)(u) * 128,                 \
                 (ldsdst) + (h) * 16384 + ldst);                                     \
    async_copy16((gbase) + (size_t)(h) * 262144 + 131072 + (size_t)(u) * 128,        \
                 (ldsdst) + (h) * 16384 + 8192 + ldst);                              \
} while (0)

#define LDA(sAp, mh) do {                                                            \
    _Pragma("unroll") for (int m = 0; m < 4; ++m) {                                  \
        a[m][0] = *(const bf16x8*)((sAp) + aRow + (mh) * 8192 + m * 2048 + c0);      \
        a[m][1] = *(const bf16x8*)((sAp) + aRow + (mh) * 8192 + m * 2048 + c1);      \
    }                                                                                \
} while (0)

#define LDB(sBp, nh) do {                                                            \
    _Pragma("unroll") for (int n = 0; n < 2; ++n) {                                  \
        b[nh][n][0] = *(const bf16x8*)((sBp) + bRow + (nh) * 4096 + n * 2048 + c0);  \
        b[nh][n][1] = *(const bf16x8*)((sBp) + bRow + (nh) * 4096 + n * 2048 + c1);  \
    }                                                                                \
} while (0)

#define MM(mh, nh) do {                                                              \
    _Pragma("unroll") for (int m = 0; m < 4; ++m)                                    \
    _Pragma("unroll") for (int n = 0; n < 2; ++n) {                                  \
        acc[(mh)*4+m][(nh)*2+n] = __builtin_amdgcn_mfma_f32_16x16x32_bf16(           \
            a[m][0], b[nh][n][0], acc[(mh)*4+m][(nh)*2+n], 0, 0, 0);                 \
        acc[(mh)*4+m][(nh)*2+n] = __builtin_amdgcn_mfma_f32_16x16x32_bf16(           \
            a[m][1], b[nh][n][1], acc[(mh)*4+m][(nh)*2+n], 0, 0, 0);                 \
    }                                                                                \
} while (0)

#define SBAR() do { __builtin_amdgcn_sched_barrier(0); __builtin_amdgcn_s_barrier(); \
                    __builtin_amdgcn_sched_barrier(0); } while (0)
#define LGK0() do { asm volatile("s_waitcnt lgkmcnt(0)" ::: "memory");               \
                    __builtin_amdgcn_sched_barrier(0); } while (0)
#define VMC(n) do { asm volatile("s_waitcnt vmcnt(" #n ")" ::: "memory");            \
                    __builtin_amdgcn_sched_barrier(0); } while (0)
#define PRI1() __builtin_amdgcn_s_setprio(1)
#define PRI0() __builtin_amdgcn_s_setprio(0)

#define KTILE(p, uA, uB) do {                                                        \
    const char* sAp = lds + (p) * 32768;                                             \
    const char* sBp = lds + 65536 + (p) * 32768;                                     \
    char* stA = lds + ((p) ^ 1) * 32768;                                             \
    char* stB = lds + 65536 + (p) * 32768;                                           \
    /* P1 */ LDA(sAp, 0); LDB(sBp, 0); STAGE(gA, (uA), 0, stA);                      \
    SBAR(); LGK0(); PRI1(); MM(0, 0); PRI0(); SBAR();                                \
    /* P2 */ LDB(sBp, 1); STAGE(gA, (uA), 1, stA);                                   \
    SBAR(); LGK0(); PRI1(); MM(0, 1); PRI0(); SBAR();                                \
    /* P3 */ LDA(sAp, 1); STAGE(gB, (uB), 0, stB);                                   \
    SBAR(); LGK0(); PRI1(); MM(1, 1); PRI0(); SBAR();                                \
    /* P4 */ STAGE(gB, (uB), 1, stB);                                                \
    SBAR(); LGK0(); PRI1(); MM(1, 0); PRI0(); VMC(4); SBAR();                        \
} while (0)

    // Prologue: A(0)->A[0], B(0)->B[0], B(1)->B[1]; wait A(0)+B(0) (vmcnt 4).
    STAGE(gA, 0, 0, lds);
    STAGE(gA, 0, 1, lds);
    STAGE(gB, 0, 0, lds + 65536);
    STAGE(gB, 0, 1, lds + 65536);
    STAGE(gB, 1, 0, lds + 65536 + 32768);
    STAGE(gB, 1, 1, lds + 65536 + 32768);
    VMC(4);
    SBAR();

    for (int tt = 0; tt < NT / 2; ++tt) {
        int t0 = tt * 2;
        { int uA = (t0 + 1) & 15, uB = (t0 + 2) & 15; KTILE(0, uA, uB); }
        { int uA = (t0 + 2) & 15, uB = (t0 + 3) & 15; KTILE(1, uA, uB); }
    }
    VMC(0);   // drain leftover staging before LDS deallocation at endpgm

    // Epilogue: C/D map col=fr, row=q*4+j. Validity == (S[i] > 0) downstream,
    // since every kept term exp((sv-p)/tau) >= e^-13.6 > 0 and p<=0 -> no mask.
    #pragma unroll
    for (int m = 0; m < 8; ++m) {
        #pragma unroll
        for (int j = 0; j < 4; ++j) {
            int i = rowBase + wm * 128 + m * 16 + q * 4 + j;
            float p  = pos[i];
            float up = TOPM * p, lo = BOTM * p;
            float rs = 0.0f;
            #pragma unroll
            for (int n = 0; n < 4; ++n) {
                float sv = acc[m][n][j];
                int col = colBase + wn * 64 + n * 16 + fr;
                if (sv <= up && sv >= lo && col != i)
                    rs += __expf((sv - p) * INV_TAU);
            }
            #pragma unroll
            for (int d = 1; d < 16; d <<= 1)
                rs += __shfl_xor(rs, d);
            if (fr == 0 && rs != 0.0f)
                atomicAdd(&S[i], rs);
        }
    }
#undef STAGE
#undef LDA
#undef LDB
#undef MM
#undef SBAR
#undef LGK0
#undef VMC
#undef PRI1
#undef PRI0
#undef KTILE
}

// ---------------------------------------------------------------------------
// Kernel 3: per_row = log1p(S_i) for rows with any negative; mean over valid.
// ---------------------------------------------------------------------------
__global__ __launch_bounds__(256) void finalize_kernel(
    const float* __restrict__ S, float* __restrict__ out)
{
    int t = threadIdx.x;
    float tot = 0.0f;
    int c = 0;
    for (int i = t; i < BATCH; i += 256) {
        float s = S[i];
        if (s > 0.0f) { tot += log1pf(s); c += 1; }
    }
    #pragma unroll
    for (int d = 32; d > 0; d >>= 1) {
        tot += __shfl_down(tot, d);
        c   += __shfl_down(c, d);
    }
    __shared__ float st[4];
    __shared__ int   sc[4];
    int lane = t & 63, w = t >> 6;
    if (lane == 0) { st[w] = tot; sc[w] = c; }
    __syncthreads();
    if (t == 0) {
        float T = st[0] + st[1] + st[2] + st[3];
        int   C = sc[0] + sc[1] + sc[2] + sc[3];
        out[0] = T / (float)(C > 0 ? C : 1);
    }
}

extern "C" void kernel_launch(void* const* d_in, const int* in_sizes, int n_in,
                              void* d_out, int out_size, void* d_ws, size_t ws_size,
                              hipStream_t stream) {
    const float* A = (const float*)d_in[0];
    const float* B = (const float*)d_in[1];

    char* ws = (char*)d_ws;
    unsigned short* An = (unsigned short*)ws;
    unsigned short* Bn = An + (size_t)BATCH * DIM;
    float* pos = (float*)(Bn + (size_t)BATCH * DIM);
    float* S   = pos + BATCH;
    float* out = (float*)d_out;

    prep_kernel<<<BATCH, 256, 0, stream>>>(A, B, An, Bn, pos, S);
    sim_loss_kernel<<<dim3(BATCH / BM * BATCH / BN / 1), 512, 0, stream>>>(An, Bn, pos, S);
    finalize_kernel<<<1, 256, 0, stream>>>(S, out);
}

// Round 3
// 212.537 us; speedup vs baseline: 1.4819x; 1.1724x over previous
//
#include <hip/hip_runtime.h>
#include <hip/hip_bf16.h>

#define BATCH 8192
#define DIM   1024
#define INV_TAU (1.0f / 0.07f)
#define TOPM 0.95f
#define BOTM 0.05f

#define BM 256
#define BN 256
#define BK 64
#define NT (DIM / BK)   // 16 K-tiles

typedef __attribute__((ext_vector_type(4))) float f32x4;
typedef __attribute__((ext_vector_type(8))) short bf16x8;

typedef __attribute__((address_space(3))) void       lds_void_t;
typedef const __attribute__((address_space(1))) void gbl_void_t;

__device__ inline void async_copy16(const void* g, void* l) {
    __builtin_amdgcn_global_load_lds((gbl_void_t*)g, (lds_void_t*)l, 16, 0, 0);
}

__device__ inline unsigned short f2bf(float f) {
    __hip_bfloat16 h = __float2bfloat16(f);
    return *reinterpret_cast<unsigned short*>(&h);
}

// ---------------------------------------------------------------------------
// Kernel 1: per-row L2 norms, exact fp32 pos (diag similarity), bf16 writes,
// zero-init of per-row accumulator S.
// ---------------------------------------------------------------------------
__global__ __launch_bounds__(256) void prep_kernel(
    const float* __restrict__ A, const float* __restrict__ B,
    unsigned short* __restrict__ An, unsigned short* __restrict__ Bn,
    float* __restrict__ pos, float* __restrict__ S)
{
    int row = blockIdx.x;
    int t = threadIdx.x;
    const float4* a4 = (const float4*)(A + (size_t)row * DIM);
    const float4* b4 = (const float4*)(B + (size_t)row * DIM);
    float4 av = a4[t];
    float4 bv = b4[t];
    float sa = av.x*av.x + av.y*av.y + av.z*av.z + av.w*av.w;
    float sb = bv.x*bv.x + bv.y*bv.y + bv.z*bv.z + bv.w*bv.w;
    float dp = av.x*bv.x + av.y*bv.y + av.z*bv.z + av.w*bv.w;
    #pragma unroll
    for (int d = 32; d > 0; d >>= 1) {
        sa += __shfl_down(sa, d);
        sb += __shfl_down(sb, d);
        dp += __shfl_down(dp, d);
    }
    __shared__ float red[3][4];
    int lane = t & 63, w = t >> 6;
    if (lane == 0) { red[0][w] = sa; red[1][w] = sb; red[2][w] = dp; }
    __syncthreads();
    sa = red[0][0] + red[0][1] + red[0][2] + red[0][3];
    sb = red[1][0] + red[1][1] + red[1][2] + red[1][3];
    dp = red[2][0] + red[2][1] + red[2][2] + red[2][3];
    float ra = rsqrtf(sa);
    float rb = rsqrtf(sb);
    if (t == 0) {
        pos[row] = dp * ra * rb;
        S[row] = 0.0f;
    }
    ushort4 oa, ob;
    oa.x = f2bf(av.x * ra); oa.y = f2bf(av.y * ra);
    oa.z = f2bf(av.z * ra); oa.w = f2bf(av.w * ra);
    ob.x = f2bf(bv.x * rb); ob.y = f2bf(bv.y * rb);
    ob.z = f2bf(bv.z * rb); ob.w = f2bf(bv.w * rb);
    ((ushort4*)(An + (size_t)row * DIM))[t] = oa;
    ((ushort4*)(Bn + (size_t)row * DIM))[t] = ob;
}

// ---------------------------------------------------------------------------
// Kernel 2: 256x256-tile 4-phase-per-K-tile pipelined MFMA GEMM + fused
// masked exp-sum. 8 waves (2M x 4N), per-wave 128x64, BK=64, double-buffered
// 128 KiB LDS. One barrier per phase; shifted ds_reads (P1: a0,b0,b1 with
// counted lgkmcnt(4); P3: a1); counted vmcnt(4) once per K-tile; setprio
// around MFMA; both-sides XOR swizzle; quadrant/XCD two-level block swizzle.
//
// Hazard ledger (steady state, per tile t, buffer p=t&1):
//  loads outstanding at P4 pre-VMC: B(t+1)x4 (left by prev VMC), A(t+1)x4
//  (P1,P2), B(t+2)h0 x2 (P3), B(t+2)h1 x2 (P4) = 12 -> vmcnt(4) drains
//  B(t+1)+A(t+1), leaves B(t+2)x4.  BAR after VMC gates all waves.
//  Stage-over-read: B[p] reads (b0,b1) issued P1, drained by P1 lgkmcnt(4) /
//  P2 lgkmcnt(0), both before BAR(P2) < P3's B-stage.  A[p^1] reads (prev
//  tile a1) drained at its P3 lgkmcnt(0) before BAR(P3) < this P1's A-stage.
// ---------------------------------------------------------------------------
__global__ __launch_bounds__(512, 2) void sim_loss_kernel(
    const unsigned short* __restrict__ An, const unsigned short* __restrict__ Bn,
    const float* __restrict__ pos, float* __restrict__ S)
{
    __shared__ char lds[131072];   // A[2]: 0,32768 ; B[2]: 65536, 98304

    int tid  = threadIdx.x;
    int lane = tid & 63;
    int wave = tid >> 6;
    int wm = wave >> 2, wn = wave & 3;   // 2x4 wave grid, 128x64 per wave
    int fr = lane & 15;
    int q  = lane >> 4;

    // Two-level swizzle: generation (256 blocks) -> 16x16 quadrant (snake),
    // XCD (bid&7) -> 4x8 rect inside the quadrant.
    int bid = blockIdx.x;
    int xcd = bid & 7, idx = bid >> 3, gen = idx >> 5, j = idx & 31;
    int qr = gen >> 1, qc = (gen & 1) ^ (qr & 1);
    int by = qr * 16 + (xcd >> 1) * 4 + (j >> 3);
    int bx = qc * 16 + (xcd & 1) * 8 + (j & 7);
    int rowBase = by * BM, colBase = bx * BN;

    f32x4 acc[8][4] = {};
    bf16x8 a[4][2];      // current mh half: 4 m-frags x 2 k-slices
    bf16x8 b[2][2][2];   // both nh halves: [nh][n][kk]

    // ds_read addressing (read-side swizzle)
    int sw = (fr & 7) << 4;
    int c0 = (q * 16) ^ sw;
    int c1 = (64 + q * 16) ^ sw;
    int aRow = (wm * 128 + fr) * 128;
    int bRow = (wn * 64 + fr) * 128;

    // staging addressing (source-side swizzle, linear LDS dest)
    int strow = tid >> 3;                                  // 0..63
    int scb   = ((tid & 7) * 16) ^ ((strow & 7) << 4);
    const char* gA = (const char*)An + (size_t)(rowBase + strow) * 2048 + scb;
    const char* gB = (const char*)Bn + (size_t)(colBase + strow) * 2048 + scb;
    int ldst = tid * 16;

#define STAGE(gbase, u, h, ldsdst) do {                                              \
    async_copy16((gbase) + (size_t)(h) * 262144 + (size_t)(u) * 128,                 \
                 (ldsdst) + (h) * 16384 + ldst);                                     \
    async_copy16((gbase) + (size_t)(h) * 262144 + 131072 + (size_t)(u) * 128,        \
                 (ldsdst) + (h) * 16384 + 8192 + ldst);                              \
} while (0)

#define LDA(sAp, mh) do {                                                            \
    _Pragma("unroll") for (int m = 0; m < 4; ++m) {                                  \
        a[m][0] = *(const bf16x8*)((sAp) + aRow + (mh) * 8192 + m * 2048 + c0);      \
        a[m][1] = *(const bf16x8*)((sAp) + aRow + (mh) * 8192 + m * 2048 + c1);      \
    }                                                                                \
} while (0)

#define LDB(sBp, nh) do {                                                            \
    _Pragma("unroll") for (int n = 0; n < 2; ++n) {                                  \
        b[nh][n][0] = *(const bf16x8*)((sBp) + bRow + (nh) * 4096 + n * 2048 + c0);  \
        b[nh][n][1] = *(const bf16x8*)((sBp) + bRow + (nh) * 4096 + n * 2048 + c1);  \
    }                                                                                \
} while (0)

#define MM(mh, nh) do {                                                              \
    _Pragma("unroll") for (int m = 0; m < 4; ++m)                                    \
    _Pragma("unroll") for (int n = 0; n < 2; ++n) {                                  \
        acc[(mh)*4+m][(nh)*2+n] = __builtin_amdgcn_mfma_f32_16x16x32_bf16(           \
            a[m][0], b[nh][n][0], acc[(mh)*4+m][(nh)*2+n], 0, 0, 0);                 \
        acc[(mh)*4+m][(nh)*2+n] = __builtin_amdgcn_mfma_f32_16x16x32_bf16(           \
            a[m][1], b[nh][n][1], acc[(mh)*4+m][(nh)*2+n], 0, 0, 0);                 \
    }                                                                                \
} while (0)

#define BAR() __builtin_amdgcn_s_barrier()
#define SCH() __builtin_amdgcn_sched_barrier(0)
#define LGKM(n) do { asm volatile("s_waitcnt lgkmcnt(" #n ")" ::: "memory");         \
                     SCH(); } while (0)
#define VMC(n)  asm volatile("s_waitcnt vmcnt(" #n ")" ::: "memory")
#define PRI1() __builtin_amdgcn_s_setprio(1)
#define PRI0() __builtin_amdgcn_s_setprio(0)

#define KTILE(p, uA, uB) do {                                                        \
    const char* sAp = lds + (p) * 32768;                                             \
    const char* sBp = lds + 65536 + (p) * 32768;                                     \
    char* stA = lds + ((p) ^ 1) * 32768;                                             \
    char* stB = lds + 65536 + (p) * 32768;                                           \
    /* P1: reads a0,b0,b1 (16); wait a0+b0 (leave b1's 4) */                         \
    LDA(sAp, 0); LDB(sBp, 0); LDB(sBp, 1); STAGE(gA, (uA), 0, stA);                  \
    LGKM(4); PRI1(); MM(0, 0); PRI0(); BAR();                                        \
    /* P2: wait b1 */                                                                \
    STAGE(gA, (uA), 1, stA);                                                         \
    LGKM(0); PRI1(); MM(0, 1); PRI0(); BAR(); SCH();                                 \
    /* P3: reads a1 (8) */                                                           \
    LDA(sAp, 1); STAGE(gB, (uB), 0, stB);                                            \
    LGKM(0); PRI1(); MM(1, 1); PRI0(); BAR();                                        \
    /* P4: no reads; drain next tile's operands */                                   \
    STAGE(gB, (uB), 1, stB);                                                         \
    PRI1(); MM(1, 0); PRI0(); VMC(4); BAR(); SCH();                                  \
} while (0)

    // Prologue: A(0)->A[0], B(0)->B[0], B(1)->B[1]; wait A(0)+B(0) (vmcnt 4).
    STAGE(gA, 0, 0, lds);
    STAGE(gA, 0, 1, lds);
    STAGE(gB, 0, 0, lds + 65536);
    STAGE(gB, 0, 1, lds + 65536);
    STAGE(gB, 1, 0, lds + 65536 + 32768);
    STAGE(gB, 1, 1, lds + 65536 + 32768);
    VMC(4);
    BAR();
    SCH();

    for (int tt = 0; tt < NT / 2; ++tt) {
        int t0 = tt * 2;
        { int uA = (t0 + 1) & 15, uB = (t0 + 2) & 15; KTILE(0, uA, uB); }
        { int uA = (t0 + 2) & 15, uB = (t0 + 3) & 15; KTILE(1, uA, uB); }
    }

    // Epilogue: C/D map col=fr, row=q*4+j. Validity == (S[i] > 0) downstream.
    #pragma unroll
    for (int m = 0; m < 8; ++m) {
        #pragma unroll
        for (int j2 = 0; j2 < 4; ++j2) {
            int i = rowBase + wm * 128 + m * 16 + q * 4 + j2;
            float p  = pos[i];
            float up = TOPM * p, lo = BOTM * p;
            float rs = 0.0f;
            #pragma unroll
            for (int n = 0; n < 4; ++n) {
                float sv = acc[m][n][j2];
                int col = colBase + wn * 64 + n * 16 + fr;
                if (sv <= up && sv >= lo && col != i)
                    rs += __expf((sv - p) * INV_TAU);
            }
            #pragma unroll
            for (int d = 1; d < 16; d <<= 1)
                rs += __shfl_xor(rs, d);
            if (fr == 0 && rs != 0.0f)
                atomicAdd(&S[i], rs);
        }
    }
    VMC(0);   // drain leftover (wrapped) staging before endpgm
#undef STAGE
#undef LDA
#undef LDB
#undef MM
#undef BAR
#undef SCH
#undef LGKM
#undef VMC
#undef PRI1
#undef PRI0
#undef KTILE
}

// ---------------------------------------------------------------------------
// Kernel 3: per_row = log1p(S_i) for rows with any negative; mean over valid.
// ---------------------------------------------------------------------------
__global__ __launch_bounds__(256) void finalize_kernel(
    const float* __restrict__ S, float* __restrict__ out)
{
    int t = threadIdx.x;
    float tot = 0.0f;
    int c = 0;
    for (int i = t; i < BATCH; i += 256) {
        float s = S[i];
        if (s > 0.0f) { tot += log1pf(s); c += 1; }
    }
    #pragma unroll
    for (int d = 32; d > 0; d >>= 1) {
        tot += __shfl_down(tot, d);
        c   += __shfl_down(c, d);
    }
    __shared__ float st[4];
    __shared__ int   sc[4];
    int lane = t & 63, w = t >> 6;
    if (lane == 0) { st[w] = tot; sc[w] = c; }
    __syncthreads();
    if (t == 0) {
        float T = st[0] + st[1] + st[2] + st[3];
        int   C = sc[0] + sc[1] + sc[2] + sc[3];
        out[0] = T / (float)(C > 0 ? C : 1);
    }
}

extern "C" void kernel_launch(void* const* d_in, const int* in_sizes, int n_in,
                              void* d_out, int out_size, void* d_ws, size_t ws_size,
                              hipStream_t stream) {
    const float* A = (const float*)d_in[0];
    const float* B = (const float*)d_in[1];

    char* ws = (char*)d_ws;
    unsigned short* An = (unsigned short*)ws;
    unsigned short* Bn = An + (size_t)BATCH * DIM;
    float* pos = (float*)(Bn + (size_t)BATCH * DIM);
    float* S   = pos + BATCH;
    float* out = (float*)d_out;

    prep_kernel<<<BATCH, 256, 0, stream>>>(A, B, An, Bn, pos, S);
    sim_loss_kernel<<<dim3(BATCH / BM * BATCH / BN), 512, 0, stream>>>(An, Bn, pos, S);
    finalize_kernel<<<1, 256, 0, stream>>>(S, out);
}

// Round 4
// 202.566 us; speedup vs baseline: 1.5548x; 1.0492x over previous
//
#include <hip/hip_runtime.h>
#include <hip/hip_bf16.h>

#define BATCH 8192
#define DIM   1024
#define INV_TAU (1.0f / 0.07f)
#define TOPM 0.95f
#define BOTM 0.05f

#define BM 256
#define BN 256
#define BK 64
#define NT (DIM / BK)   // 16 K-tiles per output tile

typedef __attribute__((ext_vector_type(4))) float f32x4;
typedef __attribute__((ext_vector_type(8))) short bf16x8;

typedef __attribute__((address_space(3))) void       lds_void_t;
typedef const __attribute__((address_space(1))) void gbl_void_t;

__device__ inline void async_copy16(const void* g, void* l) {
    __builtin_amdgcn_global_load_lds((gbl_void_t*)g, (lds_void_t*)l, 16, 0, 0);
}

__device__ inline unsigned short f2bf(float f) {
    __hip_bfloat16 h = __float2bfloat16(f);
    return *reinterpret_cast<unsigned short*>(&h);
}

// ---------------------------------------------------------------------------
// Kernel 1: per-row L2 norms, exact fp32 pos (diag similarity), bf16 writes,
// zero-init of per-row accumulator S.
// ---------------------------------------------------------------------------
__global__ __launch_bounds__(256) void prep_kernel(
    const float* __restrict__ A, const float* __restrict__ B,
    unsigned short* __restrict__ An, unsigned short* __restrict__ Bn,
    float* __restrict__ pos, float* __restrict__ S)
{
    int row = blockIdx.x;
    int t = threadIdx.x;
    const float4* a4 = (const float4*)(A + (size_t)row * DIM);
    const float4* b4 = (const float4*)(B + (size_t)row * DIM);
    float4 av = a4[t];
    float4 bv = b4[t];
    float sa = av.x*av.x + av.y*av.y + av.z*av.z + av.w*av.w;
    float sb = bv.x*bv.x + bv.y*bv.y + bv.z*bv.z + bv.w*bv.w;
    float dp = av.x*bv.x + av.y*bv.y + av.z*bv.z + av.w*bv.w;
    #pragma unroll
    for (int d = 32; d > 0; d >>= 1) {
        sa += __shfl_down(sa, d);
        sb += __shfl_down(sb, d);
        dp += __shfl_down(dp, d);
    }
    __shared__ float red[3][4];
    int lane = t & 63, w = t >> 6;
    if (lane == 0) { red[0][w] = sa; red[1][w] = sb; red[2][w] = dp; }
    __syncthreads();
    sa = red[0][0] + red[0][1] + red[0][2] + red[0][3];
    sb = red[1][0] + red[1][1] + red[1][2] + red[1][3];
    dp = red[2][0] + red[2][1] + red[2][2] + red[2][3];
    float ra = rsqrtf(sa);
    float rb = rsqrtf(sb);
    if (t == 0) {
        pos[row] = dp * ra * rb;
        S[row] = 0.0f;
    }
    ushort4 oa, ob;
    oa.x = f2bf(av.x * ra); oa.y = f2bf(av.y * ra);
    oa.z = f2bf(av.z * ra); oa.w = f2bf(av.w * ra);
    ob.x = f2bf(bv.x * rb); ob.y = f2bf(bv.y * rb);
    ob.z = f2bf(bv.z * rb); ob.w = f2bf(bv.w * rb);
    ((ushort4*)(An + (size_t)row * DIM))[t] = oa;
    ((ushort4*)(Bn + (size_t)row * DIM))[t] = ob;
}

// ---------------------------------------------------------------------------
// Kernel 2: PERSISTENT 256x256-tile 4-phase pipelined MFMA GEMM + fused
// masked exp-sum. Grid = 256 (1 block/CU); each block does 4 output tiles in
// snake-quadrant order (g0-g1 share A-panel, g1-g2 share B-panel). The mod-16
// staging wrap at K-tiles 14/15 is redirected to the NEXT tile's panels, so
// the K-pipeline never drains across tiles and next-tile staging latency
// hides under the epilogue.
//
// Hazard ledger (steady state, tile t, buffer p=t&1) — unchanged from r3:
//  at P4 pre-VMC: [B(t+1) 4][A(t+1) 4][B(t+2) 4] -> vmcnt(4) drains
//  B(t+1)+A(t+1), leaves B(t+2). Epilogue atomics add vmcnt entries; the
//  next tile's VMC(4) then also waits those (over-drain: safe).
//  Stage-over-read: B[p] reads drained by P2 LGKM(0) before BAR(P2) < P3
//  stage; A[p^1] reads drained at P3 LGKM(0) before BAR(P3) < next P1 stage.
// ---------------------------------------------------------------------------
__global__ __launch_bounds__(512, 2) void sim_loss_kernel(
    const unsigned short* __restrict__ An, const unsigned short* __restrict__ Bn,
    const float* __restrict__ pos, float* __restrict__ S)
{
    __shared__ char lds[131072];   // A[2]: 0,32768 ; B[2]: 65536, 98304

    int tid  = threadIdx.x;
    int lane = tid & 63;
    int wave = tid >> 6;
    int wm = wave >> 2, wn = wave & 3;   // 2x4 wave grid, 128x64 per wave
    int fr = lane & 15;
    int q  = lane >> 4;

    int bid = blockIdx.x;   // 0..255

    // Two-level swizzle: tile g of block bid = global index g*256+bid.
    // gen = g -> 16x16 quadrant (snake); XCD (bid&7) -> 4x8 rect inside it.
#define BASES(g, rB, cB) do {                                                        \
    int xcd_ = bid & 7, jj_ = bid >> 3;                                              \
    int qr_ = (g) >> 1, qc_ = ((g) & 1) ^ (qr_ & 1);                                 \
    (rB) = (qr_ * 16 + (xcd_ >> 1) * 4 + (jj_ >> 3)) * BM;                           \
    (cB) = (qc_ * 16 + (xcd_ & 1) * 8 + (jj_ & 7)) * BN;                             \
} while (0)

    f32x4 acc[8][4] = {};
    bf16x8 a[4][2];      // current mh half: 4 m-frags x 2 k-slices
    bf16x8 b[2][2][2];   // both nh halves: [nh][n][kk]

    // ds_read addressing (read-side swizzle)
    int sw = (fr & 7) << 4;
    int c0 = (q * 16) ^ sw;
    int c1 = (64 + q * 16) ^ sw;
    int aRow = (wm * 128 + fr) * 128;
    int bRow = (wn * 64 + fr) * 128;

    // staging addressing (source-side swizzle, linear LDS dest)
    int strow = tid >> 3;                                  // 0..63
    int scb   = ((tid & 7) * 16) ^ ((strow & 7) << 4);
    int ldst = tid * 16;

#define PANELS(rB, cB, pA, pB) do {                                                  \
    (pA) = (const char*)An + (size_t)((rB) + strow) * 2048 + scb;                    \
    (pB) = (const char*)Bn + (size_t)((cB) + strow) * 2048 + scb;                    \
} while (0)

#define STAGE(gbase, u, h, ldsdst) do {                                              \
    async_copy16((gbase) + (size_t)(h) * 262144 + (size_t)(u) * 128,                 \
                 (ldsdst) + (h) * 16384 + ldst);                                     \
    async_copy16((gbase) + (size_t)(h) * 262144 + 131072 + (size_t)(u) * 128,        \
                 (ldsdst) + (h) * 16384 + 8192 + ldst);                              \
} while (0)

#define LDA(sAp, mh) do {                                                            \
    _Pragma("unroll") for (int m = 0; m < 4; ++m) {                                  \
        a[m][0] = *(const bf16x8*)((sAp) + aRow + (mh) * 8192 + m * 2048 + c0);      \
        a[m][1] = *(const bf16x8*)((sAp) + aRow + (mh) * 8192 + m * 2048 + c1);      \
    }                                                                                \
} while (0)

#define LDB(sBp, nh) do {                                                            \
    _Pragma("unroll") for (int n = 0; n < 2; ++n) {                                  \
        b[nh][n][0] = *(const bf16x8*)((sBp) + bRow + (nh) * 4096 + n * 2048 + c0);  \
        b[nh][n][1] = *(const bf16x8*)((sBp) + bRow + (nh) * 4096 + n * 2048 + c1);  \
    }                                                                                \
} while (0)

#define MM(mh, nh) do {                                                              \
    _Pragma("unroll") for (int m = 0; m < 4; ++m)                                    \
    _Pragma("unroll") for (int n = 0; n < 2; ++n) {                                  \
        acc[(mh)*4+m][(nh)*2+n] = __builtin_amdgcn_mfma_f32_16x16x32_bf16(           \
            a[m][0], b[nh][n][0], acc[(mh)*4+m][(nh)*2+n], 0, 0, 0);                 \
        acc[(mh)*4+m][(nh)*2+n] = __builtin_amdgcn_mfma_f32_16x16x32_bf16(           \
            a[m][1], b[nh][n][1], acc[(mh)*4+m][(nh)*2+n], 0, 0, 0);                 \
    }                                                                                \
} while (0)

#define BAR() __builtin_amdgcn_s_barrier()
#define SCH() __builtin_amdgcn_sched_barrier(0)
#define LGKM(n) do { asm volatile("s_waitcnt lgkmcnt(" #n ")" ::: "memory");         \
                     SCH(); } while (0)
#define VMC(n)  asm volatile("s_waitcnt vmcnt(" #n ")" ::: "memory")
#define PRI1() __builtin_amdgcn_s_setprio(1)
#define PRI0() __builtin_amdgcn_s_setprio(0)

#define KTILE(p, gA_, uA, gB_, uB) do {                                              \
    const char* sAp = lds + (p) * 32768;                                             \
    const char* sBp = lds + 65536 + (p) * 32768;                                     \
    char* stA = lds + ((p) ^ 1) * 32768;                                             \
    char* stB = lds + 65536 + (p) * 32768;                                           \
    /* P1: reads a0,b0,b1 (16); wait a0+b0 (leave b1's 4) */                         \
    LDA(sAp, 0); LDB(sBp, 0); LDB(sBp, 1); STAGE((gA_), (uA), 0, stA);               \
    LGKM(4); PRI1(); MM(0, 0); PRI0(); BAR();                                        \
    /* P2: wait b1 */                                                                \
    STAGE((gA_), (uA), 1, stA);                                                      \
    LGKM(0); PRI1(); MM(0, 1); PRI0(); BAR(); SCH();                                 \
    /* P3: reads a1 (8) */                                                           \
    LDA(sAp, 1); STAGE((gB_), (uB), 0, stB);                                         \
    LGKM(0); PRI1(); MM(1, 1); PRI0(); BAR();                                        \
    /* P4: no reads; drain next K-tile's operands */                                 \
    STAGE((gB_), (uB), 1, stB);                                                      \
    PRI1(); MM(1, 0); PRI0(); VMC(4); BAR(); SCH();                                  \
} while (0)

    int rowB, colB;
    BASES(0, rowB, colB);
    const char *gAc, *gBc;
    PANELS(rowB, colB, gAc, gBc);

    // Prologue (once): A(0)->A[0], B(0)->B[0], B(1)->B[1]; wait to vmcnt 4.
    STAGE(gAc, 0, 0, lds);
    STAGE(gAc, 0, 1, lds);
    STAGE(gBc, 0, 0, lds + 65536);
    STAGE(gBc, 0, 1, lds + 65536);
    STAGE(gBc, 1, 0, lds + 65536 + 32768);
    STAGE(gBc, 1, 1, lds + 65536 + 32768);
    VMC(4);
    BAR();
    SCH();

    #pragma unroll 1
    for (int g = 0; g < 4; ++g) {
        int gn = (g < 3) ? g + 1 : 3;
        int rowBn, colBn;
        BASES(gn, rowBn, colBn);
        const char *gAn2, *gBn2;
        PANELS(rowBn, colBn, gAn2, gBn2);

        #pragma unroll 1
        for (int tt = 0; tt < 7; ++tt) {
            KTILE(0, gAc, 2 * tt + 1, gBc, 2 * tt + 2);
            KTILE(1, gAc, 2 * tt + 2, gBc, 2 * tt + 3);
        }
        // K-tiles 14/15: wrapped stages fetch the NEXT output tile's panels.
        KTILE(0, gAc, 15, gBn2, 0);
        KTILE(1, gAn2, 0, gBn2, 1);

        // Epilogue for tile g (registers + atomics only; next tile's first
        // operands are already in flight / drained per the ledger).
        #pragma unroll
        for (int m = 0; m < 8; ++m) {
            #pragma unroll
            for (int j2 = 0; j2 < 4; ++j2) {
                int i = rowB + wm * 128 + m * 16 + q * 4 + j2;
                float p  = pos[i];
                float up = TOPM * p, lo = BOTM * p;
                float rs = 0.0f;
                #pragma unroll
                for (int n = 0; n < 4; ++n) {
                    float sv = acc[m][n][j2];
                    int col = colB + wn * 64 + n * 16 + fr;
                    if (sv <= up && sv >= lo && col != i)
                        rs += __expf((sv - p) * INV_TAU);
                }
                #pragma unroll
                for (int d = 1; d < 16; d <<= 1)
                    rs += __shfl_xor(rs, d);
                if (fr == 0 && rs != 0.0f)
                    atomicAdd(&S[i], rs);
            }
        }
        #pragma unroll
        for (int m2 = 0; m2 < 8; ++m2)
            #pragma unroll
            for (int n2 = 0; n2 < 4; ++n2)
                acc[m2][n2] = (f32x4){0.0f, 0.0f, 0.0f, 0.0f};

        gAc = gAn2; gBc = gBn2; rowB = rowBn; colB = colBn;
    }
    VMC(0);   // drain leftover (redundant g=3) staging + atomics before endpgm

#undef BASES
#undef PANELS
#undef STAGE
#undef LDA
#undef LDB
#undef MM
#undef BAR
#undef SCH
#undef LGKM
#undef VMC
#undef PRI1
#undef PRI0
#undef KTILE
}

// ---------------------------------------------------------------------------
// Kernel 3: per_row = log1p(S_i) for rows with any negative; mean over valid.
// ---------------------------------------------------------------------------
__global__ __launch_bounds__(256) void finalize_kernel(
    const float* __restrict__ S, float* __restrict__ out)
{
    int t = threadIdx.x;
    float tot = 0.0f;
    int c = 0;
    for (int i = t; i < BATCH; i += 256) {
        float s = S[i];
        if (s > 0.0f) { tot += log1pf(s); c += 1; }
    }
    #pragma unroll
    for (int d = 32; d > 0; d >>= 1) {
        tot += __shfl_down(tot, d);
        c   += __shfl_down(c, d);
    }
    __shared__ float st[4];
    __shared__ int   sc[4];
    int lane = t & 63, w = t >> 6;
    if (lane == 0) { st[w] = tot; sc[w] = c; }
    __syncthreads();
    if (t == 0) {
        float T = st[0] + st[1] + st[2] + st[3];
        int   C = sc[0] + sc[1] + sc[2] + sc[3];
        out[0] = T / (float)(C > 0 ? C : 1);
    }
}

extern "C" void kernel_launch(void* const* d_in, const int* in_sizes, int n_in,
                              void* d_out, int out_size, void* d_ws, size_t ws_size,
                              hipStream_t stream) {
    const float* A = (const float*)d_in[0];
    const float* B = (const float*)d_in[1];

    char* ws = (char*)d_ws;
    unsigned short* An = (unsigned short*)ws;
    unsigned short* Bn = An + (size_t)BATCH * DIM;
    float* pos = (float*)(Bn + (size_t)BATCH * DIM);
    float* S   = pos + BATCH;
    float* out = (float*)d_out;

    prep_kernel<<<BATCH, 256, 0, stream>>>(A, B, An, Bn, pos, S);
    sim_loss_kernel<<<256, 512, 0, stream>>>(An, Bn, pos, S);
    finalize_kernel<<<1, 256, 0, stream>>>(S, out);
}